// Round 7
// baseline (2712.595 us; speedup 1.0000x reference)
//
#include <hip/hip_runtime.h>

// GCN(3 layers) + MLP(4 layers), N=50000, E=800000, out = N x 8 bf16.
// NOTE: do NOT include <hip/hip_bf16.h> — it breaks this harness's build
// (rounds 1-4 fell back to a stub; round 5 proved it). Manual bf16 ushort ops.
// Dtype runtime-detection: flagI (edge_index int64 vs int32), flagF (floats
// fp32 vs packed bf16). All internal math fp32.
//
// R7 change: GEMM rewritten as LDS-staged, 8-rows-per-wave kernel.
// Old wave-per-row GEMM was latency-bound on L2 W-reads (563us @ VALUBusy 19%
// for the 256x128 layer). New: W staged in LDS in K=32 chunks; each LDS read
// feeds 8 FMAs (8 rows/wave) -> FMA-bound.

#define GN 50000
#define GE 800000
#define KC 32

__device__ __forceinline__ float ar1_b2f(unsigned short h) {
    return __uint_as_float(((unsigned)h) << 16);
}
__device__ __forceinline__ unsigned short ar1_f2b(float f) {
    unsigned u = __float_as_uint(f);
    u = u + 0x7FFFu + ((u >> 16) & 1u);   // round-to-nearest-even
    return (unsigned short)(u >> 16);
}

__global__ void ar1_zero(int* p, int n) {
    int i = blockIdx.x * 256 + threadIdx.x;
    if (i < n) p[i] = 0;
}

// flagI[0]=1 => edge_index is int64
__global__ void ar1_detect_idx(const int* ei, int* flagI) {
    __shared__ int cnt;
    if (threadIdx.x == 0) cnt = 0;
    __syncthreads();
    if (ei[2 * threadIdx.x + 1] != 0) atomicAdd(&cnt, 1);
    __syncthreads();
    if (threadIdx.x == 0) flagI[0] = (cnt < 8) ? 1 : 0;
}

// flagF[0]=1 => float tensors are fp32; 0 => packed bf16 (see R6 notes).
__global__ void ar1_detect_f(const unsigned short* xw, int* flagF) {
    __shared__ int cnt;
    if (threadIdx.x == 0) cnt = 0;
    __syncthreads();
    unsigned short w = xw[2 * threadIdx.x];
    int ex = (w >> 7) & 0xFF;
    if (w == 0 || (ex >= 90 && ex <= 150)) atomicAdd(&cnt, 1);
    __syncthreads();
    if (threadIdx.x == 0) flagF[0] = (cnt > 200) ? 0 : 1;
}

__global__ void ar1_count(const int* ei, const int* flagI, int* indeg, int E) {
    int e = blockIdx.x * 256 + threadIdx.x;
    if (e < E) {
        int d = flagI[0] ? ei[2 * (E + e)] : ei[E + e];
        if ((unsigned)d < (unsigned)GN) atomicAdd(&indeg[d], 1);
    }
}

__global__ void ar1_scan1(const int* indeg, int* offsets, int* blksum, int n) {
    __shared__ int sm[256];
    int tid = threadIdx.x;
    int i = blockIdx.x * 256 + tid;
    int v = (i < n) ? indeg[i] : 0;
    sm[tid] = v;
    __syncthreads();
    for (int off = 1; off < 256; off <<= 1) {
        int t = (tid >= off) ? sm[tid - off] : 0;
        __syncthreads();
        sm[tid] += t;
        __syncthreads();
    }
    if (i < n) offsets[i] = sm[tid] - v;
    if (tid == 255) blksum[blockIdx.x] = sm[255];
}

__global__ void ar1_scan2(const int* blksum, int* blkbase, int nb) {
    __shared__ int sm[256];
    int tid = threadIdx.x;
    int v = (tid < nb) ? blksum[tid] : 0;
    sm[tid] = v;
    __syncthreads();
    for (int off = 1; off < 256; off <<= 1) {
        int t = (tid >= off) ? sm[tid - off] : 0;
        __syncthreads();
        sm[tid] += t;
        __syncthreads();
    }
    if (tid < nb) blkbase[tid] = sm[tid] - v;
}

__global__ void ar1_scan3(const int* indeg, int* offsets, int* cursor,
                          const int* blkbase, float* dinv, int n) {
    int i = blockIdx.x * 256 + threadIdx.x;
    if (i < n) {
        int o = offsets[i] + blkbase[blockIdx.x];
        offsets[i] = o;
        cursor[i] = o;
        dinv[i] = rsqrtf((float)(indeg[i] + 1));   // +1: self loop
    }
}

__global__ void ar1_fill(const int* ei, const int* flagI, int* cursor,
                         int* csr, int E) {
    int e = blockIdx.x * 256 + threadIdx.x;
    if (e < E) {
        int is64 = flagI[0];
        int s = is64 ? ei[2 * e] : ei[e];
        int d = is64 ? ei[2 * (E + e)] : ei[E + e];
        if ((unsigned)s < (unsigned)GN && (unsigned)d < (unsigned)GN) {
            int p = atomicAdd(&cursor[d], 1);
            csr[p] = s;
        }
    }
}

// convert float tensor (fp32 or packed-bf16, per flagF) to fp32
__global__ void ar1_cvt(const void* src, float* dst, int n, const int* flagF) {
    int i = blockIdx.x * 256 + threadIdx.x;
    if (i < n) {
        if (flagF[0]) dst[i] = ((const float*)src)[i];
        else          dst[i] = ar1_b2f(((const unsigned short*)src)[i]);
    }
}

// ---------------- LDS-staged GEMM -------------------------------------------
// C[GN,M] = A[GN,K] @ W[K,M] (+bias)(+relu). M compile-time (96/256/128/64),
// K runtime multiple of 32. 256 threads = 4 waves; block covers 32 rows
// (8 rows per wave). W staged in LDS in KC=32 chunks; lane covers columns
// j = t*64+lane (t < JT). Each LDS W-read feeds 8 FMAs.
template <int M, int JT>
__global__ void ar1_gemm2(const float* __restrict__ A, const float* __restrict__ W,
                          const float* __restrict__ bias, float* __restrict__ C,
                          int K, int relu) {
    __shared__ float WL[KC * M];
    int tid = (int)threadIdx.x;
    int wv = tid >> 6, lane = tid & 63;
    int rowBase = (int)blockIdx.x * 32 + wv * 8;

    float acc[8][JT];
#pragma unroll
    for (int r = 0; r < 8; r++)
#pragma unroll
        for (int t = 0; t < JT; t++) acc[r][t] = 0.f;

    for (int kc = 0; kc < K; kc += KC) {
        // stage W[kc..kc+KC) into LDS (coalesced, conflict-free)
#pragma unroll
        for (int kk = wv; kk < KC; kk += 4)
#pragma unroll
            for (int j = lane; j < M; j += 64)
                WL[kk * M + j] = W[(size_t)(kc + kk) * M + j];
        __syncthreads();

        for (int kk4 = 0; kk4 < KC; kk4 += 4) {
            float a[8][4];
#pragma unroll
            for (int r = 0; r < 8; r++) {
                int row = rowBase + r;
                // rows >= GN read in-workspace garbage; acc never stored
                int rr = (row < GN) ? row : (GN - 1);
                float4 v = ((const float4*)(A + (size_t)rr * K))[(kc + kk4) >> 2];
                a[r][0] = v.x; a[r][1] = v.y; a[r][2] = v.z; a[r][3] = v.w;
            }
#pragma unroll
            for (int kk0 = 0; kk0 < 4; kk0++) {
#pragma unroll
                for (int t = 0; t < JT; t++) {
                    int j = t * 64 + lane;
                    float w = (j < M) ? WL[(kk4 + kk0) * M + j] : 0.f;
#pragma unroll
                    for (int r = 0; r < 8; r++) acc[r][t] += a[r][kk0] * w;
                }
            }
        }
        __syncthreads();
    }

#pragma unroll
    for (int r = 0; r < 8; r++) {
        int row = rowBase + r;
        if (row < GN) {
#pragma unroll
            for (int t = 0; t < JT; t++) {
                int j = t * 64 + lane;
                if (j < M) {
                    float v = acc[r][t];
                    if (bias) v += bias[j];
                    if (relu) v = fmaxf(v, 0.f);
                    C[(size_t)row * M + j] = v;
                }
            }
        }
    }
}

// GCN aggregate (96 feats) + bias + BN(eval) + ReLU
__global__ void ar1_agg(const float* H, const int* offsets, const int* indeg,
                        const int* csr, const float* dinv,
                        const float* bias, const float* gamma, const float* beta,
                        float* Out) {
    __shared__ int   s_src[128];
    __shared__ float s_w[128];
    int node = blockIdx.x;
    int tid = threadIdx.x;
    float di = dinv[node];
    int off = offsets[node];
    int cnt = indeg[node];
    float acc = 0.f;
    for (int base = 0; base < cnt; base += 128) {
        int m = cnt - base;
        if (m > 128) m = 128;
        if (tid < m) {
            int s = csr[off + base + tid];
            if ((unsigned)s >= (unsigned)GN) s = node;
            s_src[tid] = s;
            s_w[tid] = dinv[s] * di;
        }
        __syncthreads();
        if (tid < 96) {
            for (int e = 0; e < m; e++)
                acc += s_w[e] * H[(size_t)s_src[e] * 96 + tid];
        }
        __syncthreads();
    }
    if (tid < 96) {
        acc += di * di * H[(size_t)node * 96 + tid];   // self loop
        float v = acc + bias[tid];
        v = v * 0.9999950000374997f * gamma[tid] + beta[tid];  // 1/sqrt(1+1e-5)
        Out[(size_t)node * 96 + tid] = fmaxf(v, 0.f);
    }
}

// final 64->8 layer: writes fp32 or bf16 per flagF
__global__ void Arthur1_16458314678864_kernel(const float* A, const float* W,
                                              const float* bias, void* out,
                                              const int* flagF) {
    int i = blockIdx.x * 256 + threadIdx.x;
    if (i >= GN * 8) return;
    int node = i >> 3;
    int j = i & 7;
    const float* Ar = A + (size_t)node * 64;
    float v = bias[j];
    for (int k = 0; k < 64; k++) v += Ar[k] * W[k * 8 + j];
    if (flagF[0]) ((float*)out)[i] = v;
    else ((unsigned short*)out)[i] = ar1_f2b(v);
}

extern "C" void kernel_launch(void* const* d_in, const int* in_sizes, int n_in,
                              void* d_out, int out_size, void* d_ws, size_t ws_size,
                              hipStream_t stream) {
    (void)in_sizes; (void)n_in; (void)out_size;

    // workspace layout
    char* p = (char*)d_ws;
    float* bufB = (float*)p;  p += (size_t)GN * 256 * 4;
    float* bufA = (float*)p;  p += (size_t)GN * 128 * 4;
    int* indeg  = (int*)p;    p += (size_t)GN * 4;
    int* offs   = (int*)p;    p += (size_t)GN * 4;
    int* cursor = (int*)p;    p += (size_t)GN * 4;
    int* blksum = (int*)p;    p += 1024;
    int* blkbase= (int*)p;    p += 1024;
    int* flagI  = (int*)p;    p += 1024;
    int* flagF  = (int*)p;    p += 1024;
    float* dinv = (float*)p;  p += (size_t)GN * 4;
    int* csr    = (int*)p;    p += (size_t)GE * 4;
    float* war  = (float*)p;  p += (size_t)92000 * 4;
    size_t need = (size_t)(p - (char*)d_ws);
    if (ws_size < need) {
        hipMemsetAsync(d_out, 0x41, (size_t)GN * 8 * 2, stream);  // marker 12.06
        return;
    }

    // converted-weight arena
    int wn[20] = {6144, 96, 96, 96, 9216, 96, 96, 96, 9216, 96, 96, 96,
                  24576, 256, 32768, 128, 8192, 64, 512, 8};
    float* wd[20];
    {
        float* q = war;
        for (int i = 0; i < 20; i++) { wd[i] = q; q += wn[i]; }
    }

    const int* ei = (const int*)d_in[1];
    const int NB = (GN + 255) / 256;
    const int EB = (GE + 255) / 256;

    ar1_detect_idx<<<1, 256, 0, stream>>>(ei, flagI);
    ar1_detect_f<<<1, 256, 0, stream>>>((const unsigned short*)d_in[0], flagF);
    ar1_zero<<<NB, 256, 0, stream>>>(indeg, GN);
    ar1_count<<<EB, 256, 0, stream>>>(ei, flagI, indeg, GE);
    ar1_scan1<<<NB, 256, 0, stream>>>(indeg, offs, blksum, GN);
    ar1_scan2<<<1, 256, 0, stream>>>(blksum, blkbase, NB);
    ar1_scan3<<<NB, 256, 0, stream>>>(indeg, offs, cursor, blkbase, dinv, GN);
    ar1_fill<<<EB, 256, 0, stream>>>(ei, flagI, cursor, csr, GE);

    ar1_cvt<<<(GN * 64 + 255) / 256, 256, 0, stream>>>(d_in[0], bufA, GN * 64, flagF);
    for (int i = 0; i < 20; i++)
        ar1_cvt<<<(wn[i] + 255) / 256, 256, 0, stream>>>(d_in[2 + i], wd[i], wn[i], flagF);

    const int GB2 = (GN + 31) / 32;   // 32 rows per block

    // GCN 1..3
    ar1_gemm2<96, 2><<<GB2, 256, 0, stream>>>(bufA, wd[0], (const float*)0, bufB, 64, 0);
    ar1_agg<<<GN, 128, 0, stream>>>(bufB, offs, indeg, csr, dinv, wd[1], wd[2], wd[3], bufA);
    ar1_gemm2<96, 2><<<GB2, 256, 0, stream>>>(bufA, wd[4], (const float*)0, bufB, 96, 0);
    ar1_agg<<<GN, 128, 0, stream>>>(bufB, offs, indeg, csr, dinv, wd[5], wd[6], wd[7], bufA);
    ar1_gemm2<96, 2><<<GB2, 256, 0, stream>>>(bufA, wd[8], (const float*)0, bufB, 96, 0);
    ar1_agg<<<GN, 128, 0, stream>>>(bufB, offs, indeg, csr, dinv, wd[9], wd[10], wd[11], bufA);

    // MLP: 96->256->128->64->8
    ar1_gemm2<256, 4><<<GB2, 256, 0, stream>>>(bufA, wd[12], wd[13], bufB, 96, 1);
    ar1_gemm2<128, 2><<<GB2, 256, 0, stream>>>(bufB, wd[14], wd[15], bufA, 256, 1);
    ar1_gemm2<64, 1><<<GB2, 256, 0, stream>>>(bufA, wd[16], wd[17], bufB, 128, 1);
    Arthur1_16458314678864_kernel<<<(GN * 8 + 255) / 256, 256, 0, stream>>>(
        bufB, wd[18], wd[19], d_out, flagF);
}

// Round 8
// 1527.134 us; speedup vs baseline: 1.7763x; 1.7763x over previous
//
#include <hip/hip_runtime.h>

// GCN(3 layers) + MLP(4 layers), N=50000, E=800000, out = N x 8 bf16.
// NOTE: do NOT include <hip/hip_bf16.h> — breaks this harness's build
// (rounds 1-4 fell back to a stub; round 5 proved it). Manual bf16 ushort ops.
// Dtype runtime-detection: flagI (edge_index int64 vs int32), flagF (floats
// fp32 vs packed bf16). All internal math fp32.
//
// R8 change: __launch_bounds__(256,2) on the LDS-staged GEMM. R7 shipped it
// without launch bounds -> compiler capped VGPR=64 and spilled acc/a arrays
// to scratch: 1.46 GB WRITE_SIZE per M=96 GEMM (ideal 19 MB), 75x write
// amplification, 766us/dispatch + 31ms first-touch outliers. Cap 2 waves/EU
// (<=256 VGPR) so the ~100-VGPR working set stays in registers.

#define GN 50000
#define GE 800000
#define KC 32

__device__ __forceinline__ float ar1_b2f(unsigned short h) {
    return __uint_as_float(((unsigned)h) << 16);
}
__device__ __forceinline__ unsigned short ar1_f2b(float f) {
    unsigned u = __float_as_uint(f);
    u = u + 0x7FFFu + ((u >> 16) & 1u);   // round-to-nearest-even
    return (unsigned short)(u >> 16);
}

__global__ void ar1_zero(int* p, int n) {
    int i = blockIdx.x * 256 + threadIdx.x;
    if (i < n) p[i] = 0;
}

// flagI[0]=1 => edge_index is int64
__global__ void ar1_detect_idx(const int* ei, int* flagI) {
    __shared__ int cnt;
    if (threadIdx.x == 0) cnt = 0;
    __syncthreads();
    if (ei[2 * threadIdx.x + 1] != 0) atomicAdd(&cnt, 1);
    __syncthreads();
    if (threadIdx.x == 0) flagI[0] = (cnt < 8) ? 1 : 0;
}

// flagF[0]=1 => float tensors are fp32; 0 => packed bf16 (see R6 notes).
__global__ void ar1_detect_f(const unsigned short* xw, int* flagF) {
    __shared__ int cnt;
    if (threadIdx.x == 0) cnt = 0;
    __syncthreads();
    unsigned short w = xw[2 * threadIdx.x];
    int ex = (w >> 7) & 0xFF;
    if (w == 0 || (ex >= 90 && ex <= 150)) atomicAdd(&cnt, 1);
    __syncthreads();
    if (threadIdx.x == 0) flagF[0] = (cnt > 200) ? 0 : 1;
}

__global__ void ar1_count(const int* ei, const int* flagI, int* indeg, int E) {
    int e = blockIdx.x * 256 + threadIdx.x;
    if (e < E) {
        int d = flagI[0] ? ei[2 * (E + e)] : ei[E + e];
        if ((unsigned)d < (unsigned)GN) atomicAdd(&indeg[d], 1);
    }
}

__global__ void ar1_scan1(const int* indeg, int* offsets, int* blksum, int n) {
    __shared__ int sm[256];
    int tid = threadIdx.x;
    int i = blockIdx.x * 256 + tid;
    int v = (i < n) ? indeg[i] : 0;
    sm[tid] = v;
    __syncthreads();
    for (int off = 1; off < 256; off <<= 1) {
        int t = (tid >= off) ? sm[tid - off] : 0;
        __syncthreads();
        sm[tid] += t;
        __syncthreads();
    }
    if (i < n) offsets[i] = sm[tid] - v;
    if (tid == 255) blksum[blockIdx.x] = sm[255];
}

__global__ void ar1_scan2(const int* blksum, int* blkbase, int nb) {
    __shared__ int sm[256];
    int tid = threadIdx.x;
    int v = (tid < nb) ? blksum[tid] : 0;
    sm[tid] = v;
    __syncthreads();
    for (int off = 1; off < 256; off <<= 1) {
        int t = (tid >= off) ? sm[tid - off] : 0;
        __syncthreads();
        sm[tid] += t;
        __syncthreads();
    }
    if (tid < nb) blkbase[tid] = sm[tid] - v;
}

__global__ void ar1_scan3(const int* indeg, int* offsets, int* cursor,
                          const int* blkbase, float* dinv, int n) {
    int i = blockIdx.x * 256 + threadIdx.x;
    if (i < n) {
        int o = offsets[i] + blkbase[blockIdx.x];
        offsets[i] = o;
        cursor[i] = o;
        dinv[i] = rsqrtf((float)(indeg[i] + 1));   // +1: self loop
    }
}

__global__ void ar1_fill(const int* ei, const int* flagI, int* cursor,
                         int* csr, int E) {
    int e = blockIdx.x * 256 + threadIdx.x;
    if (e < E) {
        int is64 = flagI[0];
        int s = is64 ? ei[2 * e] : ei[e];
        int d = is64 ? ei[2 * (E + e)] : ei[E + e];
        if ((unsigned)s < (unsigned)GN && (unsigned)d < (unsigned)GN) {
            int p = atomicAdd(&cursor[d], 1);
            csr[p] = s;
        }
    }
}

// convert float tensor (fp32 or packed-bf16, per flagF) to fp32
__global__ void ar1_cvt(const void* src, float* dst, int n, const int* flagF) {
    int i = blockIdx.x * 256 + threadIdx.x;
    if (i < n) {
        if (flagF[0]) dst[i] = ((const float*)src)[i];
        else          dst[i] = ar1_b2f(((const unsigned short*)src)[i]);
    }
}

// ---------------- LDS-staged GEMM -------------------------------------------
// C[GN,M] = A[GN,K] @ W[K,M] (+bias)(+relu). M compile-time, K mult of 32.
// 256 threads = 4 waves; block covers 32 rows (8 rows/wave). W staged in LDS
// in KC=32 chunks; each LDS W-read feeds 8 FMAs.
template <int M, int JT>
__global__ __launch_bounds__(256, 2)
void ar1_gemm2(const float* __restrict__ A, const float* __restrict__ W,
               const float* __restrict__ bias, float* __restrict__ C,
               int K, int relu) {
    __shared__ float WL[KC * M];
    int tid = (int)threadIdx.x;
    int wv = tid >> 6, lane = tid & 63;
    int rowBase = (int)blockIdx.x * 32 + wv * 8;

    float acc[8][JT];
#pragma unroll
    for (int r = 0; r < 8; r++)
#pragma unroll
        for (int t = 0; t < JT; t++) acc[r][t] = 0.f;

    for (int kc = 0; kc < K; kc += KC) {
        // stage W[kc..kc+KC) into LDS (coalesced, conflict-free)
#pragma unroll
        for (int kk = wv; kk < KC; kk += 4)
#pragma unroll
            for (int j = lane; j < M; j += 64)
                WL[kk * M + j] = W[(size_t)(kc + kk) * M + j];
        __syncthreads();

        for (int kk4 = 0; kk4 < KC; kk4 += 4) {
            float a[8][4];
#pragma unroll
            for (int r = 0; r < 8; r++) {
                int row = rowBase + r;
                int rr = (row < GN) ? row : (GN - 1);   // clamp; never stored
                float4 v = ((const float4*)(A + (size_t)rr * K))[(kc + kk4) >> 2];
                a[r][0] = v.x; a[r][1] = v.y; a[r][2] = v.z; a[r][3] = v.w;
            }
#pragma unroll
            for (int kk0 = 0; kk0 < 4; kk0++) {
#pragma unroll
                for (int t = 0; t < JT; t++) {
                    int j = t * 64 + lane;
                    float w = (j < M) ? WL[(kk4 + kk0) * M + j] : 0.f;
#pragma unroll
                    for (int r = 0; r < 8; r++) acc[r][t] += a[r][kk0] * w;
                }
            }
        }
        __syncthreads();
    }

#pragma unroll
    for (int r = 0; r < 8; r++) {
        int row = rowBase + r;
        if (row < GN) {
#pragma unroll
            for (int t = 0; t < JT; t++) {
                int j = t * 64 + lane;
                if (j < M) {
                    float v = acc[r][t];
                    if (bias) v += bias[j];
                    if (relu) v = fmaxf(v, 0.f);
                    C[(size_t)row * M + j] = v;
                }
            }
        }
    }
}

// GCN aggregate (96 feats) + bias + BN(eval) + ReLU
__global__ void ar1_agg(const float* H, const int* offsets, const int* indeg,
                        const int* csr, const float* dinv,
                        const float* bias, const float* gamma, const float* beta,
                        float* Out) {
    __shared__ int   s_src[128];
    __shared__ float s_w[128];
    int node = blockIdx.x;
    int tid = threadIdx.x;
    float di = dinv[node];
    int off = offsets[node];
    int cnt = indeg[node];
    float acc = 0.f;
    for (int base = 0; base < cnt; base += 128) {
        int m = cnt - base;
        if (m > 128) m = 128;
        if (tid < m) {
            int s = csr[off + base + tid];
            if ((unsigned)s >= (unsigned)GN) s = node;
            s_src[tid] = s;
            s_w[tid] = dinv[s] * di;
        }
        __syncthreads();
        if (tid < 96) {
            for (int e = 0; e < m; e++)
                acc += s_w[e] * H[(size_t)s_src[e] * 96 + tid];
        }
        __syncthreads();
    }
    if (tid < 96) {
        acc += di * di * H[(size_t)node * 96 + tid];   // self loop
        float v = acc + bias[tid];
        v = v * 0.9999950000374997f * gamma[tid] + beta[tid];  // 1/sqrt(1+1e-5)
        Out[(size_t)node * 96 + tid] = fmaxf(v, 0.f);
    }
}

// final 64->8 layer: writes fp32 or bf16 per flagF
__global__ void Arthur1_16458314678864_kernel(const float* A, const float* W,
                                              const float* bias, void* out,
                                              const int* flagF) {
    int i = blockIdx.x * 256 + threadIdx.x;
    if (i >= GN * 8) return;
    int node = i >> 3;
    int j = i & 7;
    const float* Ar = A + (size_t)node * 64;
    float v = bias[j];
    for (int k = 0; k < 64; k++) v += Ar[k] * W[k * 8 + j];
    if (flagF[0]) ((float*)out)[i] = v;
    else ((unsigned short*)out)[i] = ar1_f2b(v);
}

extern "C" void kernel_launch(void* const* d_in, const int* in_sizes, int n_in,
                              void* d_out, int out_size, void* d_ws, size_t ws_size,
                              hipStream_t stream) {
    (void)in_sizes; (void)n_in; (void)out_size;

    // workspace layout
    char* p = (char*)d_ws;
    float* bufB = (float*)p;  p += (size_t)GN * 256 * 4;
    float* bufA = (float*)p;  p += (size_t)GN * 128 * 4;
    int* indeg  = (int*)p;    p += (size_t)GN * 4;
    int* offs   = (int*)p;    p += (size_t)GN * 4;
    int* cursor = (int*)p;    p += (size_t)GN * 4;
    int* blksum = (int*)p;    p += 1024;
    int* blkbase= (int*)p;    p += 1024;
    int* flagI  = (int*)p;    p += 1024;
    int* flagF  = (int*)p;    p += 1024;
    float* dinv = (float*)p;  p += (size_t)GN * 4;
    int* csr    = (int*)p;    p += (size_t)GE * 4;
    float* war  = (float*)p;  p += (size_t)92000 * 4;
    size_t need = (size_t)(p - (char*)d_ws);
    if (ws_size < need) {
        hipMemsetAsync(d_out, 0x41, (size_t)GN * 8 * 2, stream);  // marker 12.06
        return;
    }

    // converted-weight arena
    int wn[20] = {6144, 96, 96, 96, 9216, 96, 96, 96, 9216, 96, 96, 96,
                  24576, 256, 32768, 128, 8192, 64, 512, 8};
    float* wd[20];
    {
        float* q = war;
        for (int i = 0; i < 20; i++) { wd[i] = q; q += wn[i]; }
    }

    const int* ei = (const int*)d_in[1];
    const int NB = (GN + 255) / 256;
    const int EB = (GE + 255) / 256;

    ar1_detect_idx<<<1, 256, 0, stream>>>(ei, flagI);
    ar1_detect_f<<<1, 256, 0, stream>>>((const unsigned short*)d_in[0], flagF);
    ar1_zero<<<NB, 256, 0, stream>>>(indeg, GN);
    ar1_count<<<EB, 256, 0, stream>>>(ei, flagI, indeg, GE);
    ar1_scan1<<<NB, 256, 0, stream>>>(indeg, offs, blksum, GN);
    ar1_scan2<<<1, 256, 0, stream>>>(blksum, blkbase, NB);
    ar1_scan3<<<NB, 256, 0, stream>>>(indeg, offs, cursor, blkbase, dinv, GN);
    ar1_fill<<<EB, 256, 0, stream>>>(ei, flagI, cursor, csr, GE);

    ar1_cvt<<<(GN * 64 + 255) / 256, 256, 0, stream>>>(d_in[0], bufA, GN * 64, flagF);
    for (int i = 0; i < 20; i++)
        ar1_cvt<<<(wn[i] + 255) / 256, 256, 0, stream>>>(d_in[2 + i], wd[i], wn[i], flagF);

    const int GB2 = (GN + 31) / 32;   // 32 rows per block

    // GCN 1..3
    ar1_gemm2<96, 2><<<GB2, 256, 0, stream>>>(bufA, wd[0], (const float*)0, bufB, 64, 0);
    ar1_agg<<<GN, 128, 0, stream>>>(bufB, offs, indeg, csr, dinv, wd[1], wd[2], wd[3], bufA);
    ar1_gemm2<96, 2><<<GB2, 256, 0, stream>>>(bufA, wd[4], (const float*)0, bufB, 96, 0);
    ar1_agg<<<GN, 128, 0, stream>>>(bufB, offs, indeg, csr, dinv, wd[5], wd[6], wd[7], bufA);
    ar1_gemm2<96, 2><<<GB2, 256, 0, stream>>>(bufA, wd[8], (const float*)0, bufB, 96, 0);
    ar1_agg<<<GN, 128, 0, stream>>>(bufB, offs, indeg, csr, dinv, wd[9], wd[10], wd[11], bufA);

    // MLP: 96->256->128->64->8
    ar1_gemm2<256, 4><<<GB2, 256, 0, stream>>>(bufA, wd[12], wd[13], bufB, 96, 1);
    ar1_gemm2<128, 2><<<GB2, 256, 0, stream>>>(bufB, wd[14], wd[15], bufA, 256, 1);
    ar1_gemm2<64, 1><<<GB2, 256, 0, stream>>>(bufA, wd[16], wd[17], bufB, 128, 1);
    Arthur1_16458314678864_kernel<<<(GN * 8 + 255) / 256, 256, 0, stream>>>(
        bufB, wd[18], wd[19], d_out, flagF);
}

// Round 9
// 631.878 us; speedup vs baseline: 4.2929x; 2.4168x over previous
//
#include <hip/hip_runtime.h>

// GCN(3 layers) + MLP(4 layers), N=50000, E=800000, out = N x 8 bf16.
// NOTE: do NOT include <hip/hip_bf16.h> — breaks this harness's build
// (rounds 1-4 fell back to a stub; round 5 proved it). Manual bf16 ushort ops.
// Dtype runtime-detection: flagI (edge_index int64 vs int32), flagF (floats
// fp32 vs packed bf16). All internal math fp32.
//
// R9 change: GEMM v3 — both A-tile and W-chunk staged in LDS; per-thread
// state is ~60 VGPRs by construction. R8's version kept 8 rows x float4 of A
// in flight from global; compiler stopped at VGPR=128 and spilled (WRITE_SIZE
// 760 MB vs 19 MB ideal per M=96 GEMM; R7->R8 spill halved exactly as VGPR
// 64->128). LDS-A + bounded unroll makes spill structurally impossible.

#define GN 50000
#define GE 800000
#define KC 32

__device__ __forceinline__ float ar1_b2f(unsigned short h) {
    return __uint_as_float(((unsigned)h) << 16);
}
__device__ __forceinline__ unsigned short ar1_f2b(float f) {
    unsigned u = __float_as_uint(f);
    u = u + 0x7FFFu + ((u >> 16) & 1u);   // round-to-nearest-even
    return (unsigned short)(u >> 16);
}

__global__ void ar1_zero(int* p, int n) {
    int i = blockIdx.x * 256 + threadIdx.x;
    if (i < n) p[i] = 0;
}

// flagI[0]=1 => edge_index is int64
__global__ void ar1_detect_idx(const int* ei, int* flagI) {
    __shared__ int cnt;
    if (threadIdx.x == 0) cnt = 0;
    __syncthreads();
    if (ei[2 * threadIdx.x + 1] != 0) atomicAdd(&cnt, 1);
    __syncthreads();
    if (threadIdx.x == 0) flagI[0] = (cnt < 8) ? 1 : 0;
}

// flagF[0]=1 => float tensors are fp32; 0 => packed bf16 (see R6 notes).
__global__ void ar1_detect_f(const unsigned short* xw, int* flagF) {
    __shared__ int cnt;
    if (threadIdx.x == 0) cnt = 0;
    __syncthreads();
    unsigned short w = xw[2 * threadIdx.x];
    int ex = (w >> 7) & 0xFF;
    if (w == 0 || (ex >= 90 && ex <= 150)) atomicAdd(&cnt, 1);
    __syncthreads();
    if (threadIdx.x == 0) flagF[0] = (cnt > 200) ? 0 : 1;
}

__global__ void ar1_count(const int* ei, const int* flagI, int* indeg, int E) {
    int e = blockIdx.x * 256 + threadIdx.x;
    if (e < E) {
        int d = flagI[0] ? ei[2 * (E + e)] : ei[E + e];
        if ((unsigned)d < (unsigned)GN) atomicAdd(&indeg[d], 1);
    }
}

__global__ void ar1_scan1(const int* indeg, int* offsets, int* blksum, int n) {
    __shared__ int sm[256];
    int tid = threadIdx.x;
    int i = blockIdx.x * 256 + tid;
    int v = (i < n) ? indeg[i] : 0;
    sm[tid] = v;
    __syncthreads();
    for (int off = 1; off < 256; off <<= 1) {
        int t = (tid >= off) ? sm[tid - off] : 0;
        __syncthreads();
        sm[tid] += t;
        __syncthreads();
    }
    if (i < n) offsets[i] = sm[tid] - v;
    if (tid == 255) blksum[blockIdx.x] = sm[255];
}

__global__ void ar1_scan2(const int* blksum, int* blkbase, int nb) {
    __shared__ int sm[256];
    int tid = threadIdx.x;
    int v = (tid < nb) ? blksum[tid] : 0;
    sm[tid] = v;
    __syncthreads();
    for (int off = 1; off < 256; off <<= 1) {
        int t = (tid >= off) ? sm[tid - off] : 0;
        __syncthreads();
        sm[tid] += t;
        __syncthreads();
    }
    if (tid < nb) blkbase[tid] = sm[tid] - v;
}

__global__ void ar1_scan3(const int* indeg, int* offsets, int* cursor,
                          const int* blkbase, float* dinv, int n) {
    int i = blockIdx.x * 256 + threadIdx.x;
    if (i < n) {
        int o = offsets[i] + blkbase[blockIdx.x];
        offsets[i] = o;
        cursor[i] = o;
        dinv[i] = rsqrtf((float)(indeg[i] + 1));   // +1: self loop
    }
}

__global__ void ar1_fill(const int* ei, const int* flagI, int* cursor,
                         int* csr, int E) {
    int e = blockIdx.x * 256 + threadIdx.x;
    if (e < E) {
        int is64 = flagI[0];
        int s = is64 ? ei[2 * e] : ei[e];
        int d = is64 ? ei[2 * (E + e)] : ei[E + e];
        if ((unsigned)s < (unsigned)GN && (unsigned)d < (unsigned)GN) {
            int p = atomicAdd(&cursor[d], 1);
            csr[p] = s;
        }
    }
}

// convert float tensor (fp32 or packed-bf16, per flagF) to fp32
__global__ void ar1_cvt(const void* src, float* dst, int n, const int* flagF) {
    int i = blockIdx.x * 256 + threadIdx.x;
    if (i < n) {
        if (flagF[0]) dst[i] = ((const float*)src)[i];
        else          dst[i] = ar1_b2f(((const unsigned short*)src)[i]);
    }
}

// ---------------- GEMM v3: LDS-staged A and W, small register state ---------
// C[GN,M] = A[GN,K] @ W[K,M] (+bias)(+relu). M compile-time, K mult of 32.
// 256 threads = 4 waves; 32 rows/block (8 rows/wave). Per KC=32 chunk:
//   WL[kk][j] (KC*M floats, straight copy, b32 reads bank-free),
//   AL4[row][q] (32 rows x 8 float4 = 4 KB, b128 broadcast reads).
// Inner: w[4][JT] + one a4 per row -> 4*JT FMAs; per-thread live state
// acc[8][JT] + ~12 temps (~60 VGPR) -> no spill possible.
template <int M, int JT>
__global__ __launch_bounds__(256, 2)
void ar1_gemm3(const float* __restrict__ A, const float* __restrict__ W,
               const float* __restrict__ bias, float* __restrict__ C,
               int K, int relu) {
    __shared__ float  WL[KC * M];
    __shared__ float4 AL4[32 * 8];
    int tid = (int)threadIdx.x;
    int wv = tid >> 6, lane = tid & 63;
    int rowBase0 = (int)blockIdx.x * 32;

    float acc[8][JT];
#pragma unroll
    for (int r = 0; r < 8; r++)
#pragma unroll
        for (int t = 0; t < JT; t++) acc[r][t] = 0.f;

    // A-staging address for this thread: row rowBase0 + (tid>>3), q = tid&7
    int arow = rowBase0 + (tid >> 3);
    if (arow >= GN) arow = GN - 1;          // clamp; those rows never stored
    const float* Arow = A + (size_t)arow * K;

    for (int kc = 0; kc < K; kc += KC) {
        // stage W chunk (straight copy, coalesced float4)
        {
            const float4* W4 = (const float4*)(W + (size_t)kc * M);
            float4* WL4 = (float4*)WL;
            for (int idx = tid; idx < KC * M / 4; idx += 256)
                WL4[idx] = W4[idx];
        }
        // stage A tile: 32 rows x KC floats = 256 float4s, one per thread
        AL4[tid] = ((const float4*)(Arow + kc))[tid & 7];
        __syncthreads();

#pragma unroll 2
        for (int kk4 = 0; kk4 < KC; kk4 += 4) {
            float w0[JT], w1[JT], w2[JT], w3[JT];
#pragma unroll
            for (int t = 0; t < JT; t++) {
                int j = t * 64 + lane;
                if (j < M) {
                    w0[t] = WL[(kk4 + 0) * M + j];
                    w1[t] = WL[(kk4 + 1) * M + j];
                    w2[t] = WL[(kk4 + 2) * M + j];
                    w3[t] = WL[(kk4 + 3) * M + j];
                } else {
                    w0[t] = w1[t] = w2[t] = w3[t] = 0.f;
                }
            }
#pragma unroll
            for (int r = 0; r < 8; r++) {
                float4 a4 = AL4[(wv * 8 + r) * 8 + (kk4 >> 2)];  // broadcast
#pragma unroll
                for (int t = 0; t < JT; t++) {
                    acc[r][t] += a4.x * w0[t];
                    acc[r][t] += a4.y * w1[t];
                    acc[r][t] += a4.z * w2[t];
                    acc[r][t] += a4.w * w3[t];
                }
            }
        }
        __syncthreads();
    }

#pragma unroll
    for (int r = 0; r < 8; r++) {
        int row = rowBase0 + wv * 8 + r;
        if (row < GN) {
#pragma unroll
            for (int t = 0; t < JT; t++) {
                int j = t * 64 + lane;
                if (j < M) {
                    float v = acc[r][t];
                    if (bias) v += bias[j];
                    if (relu) v = fmaxf(v, 0.f);
                    C[(size_t)row * M + j] = v;
                }
            }
        }
    }
}

// GCN aggregate (96 feats) + bias + BN(eval) + ReLU
__global__ void ar1_agg(const float* H, const int* offsets, const int* indeg,
                        const int* csr, const float* dinv,
                        const float* bias, const float* gamma, const float* beta,
                        float* Out) {
    __shared__ int   s_src[128];
    __shared__ float s_w[128];
    int node = blockIdx.x;
    int tid = threadIdx.x;
    float di = dinv[node];
    int off = offsets[node];
    int cnt = indeg[node];
    float acc = 0.f;
    for (int base = 0; base < cnt; base += 128) {
        int m = cnt - base;
        if (m > 128) m = 128;
        if (tid < m) {
            int s = csr[off + base + tid];
            if ((unsigned)s >= (unsigned)GN) s = node;
            s_src[tid] = s;
            s_w[tid] = dinv[s] * di;
        }
        __syncthreads();
        if (tid < 96) {
            for (int e = 0; e < m; e++)
                acc += s_w[e] * H[(size_t)s_src[e] * 96 + tid];
        }
        __syncthreads();
    }
    if (tid < 96) {
        acc += di * di * H[(size_t)node * 96 + tid];   // self loop
        float v = acc + bias[tid];
        v = v * 0.9999950000374997f * gamma[tid] + beta[tid];  // 1/sqrt(1+1e-5)
        Out[(size_t)node * 96 + tid] = fmaxf(v, 0.f);
    }
}

// final 64->8 layer: writes fp32 or bf16 per flagF
__global__ void Arthur1_16458314678864_kernel(const float* A, const float* W,
                                              const float* bias, void* out,
                                              const int* flagF) {
    int i = blockIdx.x * 256 + threadIdx.x;
    if (i >= GN * 8) return;
    int node = i >> 3;
    int j = i & 7;
    const float* Ar = A + (size_t)node * 64;
    float v = bias[j];
    for (int k = 0; k < 64; k++) v += Ar[k] * W[k * 8 + j];
    if (flagF[0]) ((float*)out)[i] = v;
    else ((unsigned short*)out)[i] = ar1_f2b(v);
}

extern "C" void kernel_launch(void* const* d_in, const int* in_sizes, int n_in,
                              void* d_out, int out_size, void* d_ws, size_t ws_size,
                              hipStream_t stream) {
    (void)in_sizes; (void)n_in; (void)out_size;

    // workspace layout
    char* p = (char*)d_ws;
    float* bufB = (float*)p;  p += (size_t)GN * 256 * 4;
    float* bufA = (float*)p;  p += (size_t)GN * 128 * 4;
    int* indeg  = (int*)p;    p += (size_t)GN * 4;
    int* offs   = (int*)p;    p += (size_t)GN * 4;
    int* cursor = (int*)p;    p += (size_t)GN * 4;
    int* blksum = (int*)p;    p += 1024;
    int* blkbase= (int*)p;    p += 1024;
    int* flagI  = (int*)p;    p += 1024;
    int* flagF  = (int*)p;    p += 1024;
    float* dinv = (float*)p;  p += (size_t)GN * 4;
    int* csr    = (int*)p;    p += (size_t)GE * 4;
    float* war  = (float*)p;  p += (size_t)92000 * 4;
    size_t need = (size_t)(p - (char*)d_ws);
    if (ws_size < need) {
        hipMemsetAsync(d_out, 0x41, (size_t)GN * 8 * 2, stream);  // marker 12.06
        return;
    }

    // converted-weight arena
    int wn[20] = {6144, 96, 96, 96, 9216, 96, 96, 96, 9216, 96, 96, 96,
                  24576, 256, 32768, 128, 8192, 64, 512, 8};
    float* wd[20];
    {
        float* q = war;
        for (int i = 0; i < 20; i++) { wd[i] = q; q += wn[i]; }
    }

    const int* ei = (const int*)d_in[1];
    const int NB = (GN + 255) / 256;
    const int EB = (GE + 255) / 256;

    ar1_detect_idx<<<1, 256, 0, stream>>>(ei, flagI);
    ar1_detect_f<<<1, 256, 0, stream>>>((const unsigned short*)d_in[0], flagF);
    ar1_zero<<<NB, 256, 0, stream>>>(indeg, GN);
    ar1_count<<<EB, 256, 0, stream>>>(ei, flagI, indeg, GE);
    ar1_scan1<<<NB, 256, 0, stream>>>(indeg, offs, blksum, GN);
    ar1_scan2<<<1, 256, 0, stream>>>(blksum, blkbase, NB);
    ar1_scan3<<<NB, 256, 0, stream>>>(indeg, offs, cursor, blkbase, dinv, GN);
    ar1_fill<<<EB, 256, 0, stream>>>(ei, flagI, cursor, csr, GE);

    ar1_cvt<<<(GN * 64 + 255) / 256, 256, 0, stream>>>(d_in[0], bufA, GN * 64, flagF);
    for (int i = 0; i < 20; i++)
        ar1_cvt<<<(wn[i] + 255) / 256, 256, 0, stream>>>(d_in[2 + i], wd[i], wn[i], flagF);

    const int GB2 = (GN + 31) / 32;   // 32 rows per block

    // GCN 1..3
    ar1_gemm3<96, 2><<<GB2, 256, 0, stream>>>(bufA, wd[0], (const float*)0, bufB, 64, 0);
    ar1_agg<<<GN, 128, 0, stream>>>(bufB, offs, indeg, csr, dinv, wd[1], wd[2], wd[3], bufA);
    ar1_gemm3<96, 2><<<GB2, 256, 0, stream>>>(bufA, wd[4], (const float*)0, bufB, 96, 0);
    ar1_agg<<<GN, 128, 0, stream>>>(bufB, offs, indeg, csr, dinv, wd[5], wd[6], wd[7], bufA);
    ar1_gemm3<96, 2><<<GB2, 256, 0, stream>>>(bufA, wd[8], (const float*)0, bufB, 96, 0);
    ar1_agg<<<GN, 128, 0, stream>>>(bufB, offs, indeg, csr, dinv, wd[9], wd[10], wd[11], bufA);

    // MLP: 96->256->128->64->8
    ar1_gemm3<256, 4><<<GB2, 256, 0, stream>>>(bufA, wd[12], wd[13], bufB, 96, 1);
    ar1_gemm3<128, 2><<<GB2, 256, 0, stream>>>(bufB, wd[14], wd[15], bufA, 256, 1);
    ar1_gemm3<64, 1><<<GB2, 256, 0, stream>>>(bufA, wd[16], wd[17], bufB, 128, 1);
    Arthur1_16458314678864_kernel<<<(GN * 8 + 255) / 256, 256, 0, stream>>>(
        bufB, wd[18], wd[19], d_out, flagF);
}

// Round 10
// 476.738 us; speedup vs baseline: 5.6899x; 1.3254x over previous
//
#include <hip/hip_runtime.h>

// GCN(3 layers) + MLP(4 layers), N=50000, E=800000, out = N x 8 bf16.
// NOTE: do NOT include <hip/hip_bf16.h> — breaks this harness's build
// (rounds 1-4 fell back to a stub; round 5 proved it). Manual bf16 ushort ops.
// Dtype runtime-detection: flagI (edge_index int64 vs int32), flagF (floats
// fp32 vs packed bf16).
//
// R10: bf16 end-to-end. All 6 GEMMs use mfma_f32_16x16x32_bf16 (fp32 accum):
//   A: row-major bf16, lane frag A[m=lane&15][k=(lane>>4)*8+j] = 16B load.
//   B: weights pre-packed to fragment order B[k=(lane>>4)*8+j][n=lane&15].
//   C/D: col=lane&15, row=(lane>>4)*4+reg (m89-verified mapping).
// Intermediates bf16 (halves agg gather: 326->163 MB/layer). 20 small cvt
// launches fused to 1; weight packs 6; x-cast 1.

#define GN 50000
#define GE 800000

typedef __attribute__((ext_vector_type(8))) short bf16x8;
typedef __attribute__((ext_vector_type(4))) float floatx4;

__device__ __forceinline__ float ar1_b2f(unsigned short h) {
    return __uint_as_float(((unsigned)h) << 16);
}
__device__ __forceinline__ unsigned short ar1_f2b(float f) {
    unsigned u = __float_as_uint(f);
    u = u + 0x7FFFu + ((u >> 16) & 1u);   // round-to-nearest-even
    return (unsigned short)(u >> 16);
}

__global__ void ar1_zero(int* p, int n) {
    int i = blockIdx.x * 256 + threadIdx.x;
    if (i < n) p[i] = 0;
}

// flagI[0]=1 => edge_index is int64
__global__ void ar1_detect_idx(const int* ei, int* flagI) {
    __shared__ int cnt;
    if (threadIdx.x == 0) cnt = 0;
    __syncthreads();
    if (ei[2 * threadIdx.x + 1] != 0) atomicAdd(&cnt, 1);
    __syncthreads();
    if (threadIdx.x == 0) flagI[0] = (cnt < 8) ? 1 : 0;
}

// flagF[0]=1 => float tensors are fp32; 0 => packed bf16 (see R6 notes).
__global__ void ar1_detect_f(const unsigned short* xw, int* flagF) {
    __shared__ int cnt;
    if (threadIdx.x == 0) cnt = 0;
    __syncthreads();
    unsigned short w = xw[2 * threadIdx.x];
    int ex = (w >> 7) & 0xFF;
    if (w == 0 || (ex >= 90 && ex <= 150)) atomicAdd(&cnt, 1);
    __syncthreads();
    if (threadIdx.x == 0) flagF[0] = (cnt > 200) ? 0 : 1;
}

__global__ void ar1_count(const int* ei, const int* flagI, int* indeg, int E) {
    int e = blockIdx.x * 256 + threadIdx.x;
    if (e < E) {
        int d = flagI[0] ? ei[2 * (E + e)] : ei[E + e];
        if ((unsigned)d < (unsigned)GN) atomicAdd(&indeg[d], 1);
    }
}

__global__ void ar1_scan1(const int* indeg, int* offsets, int* blksum, int n) {
    __shared__ int sm[256];
    int tid = threadIdx.x;
    int i = blockIdx.x * 256 + tid;
    int v = (i < n) ? indeg[i] : 0;
    sm[tid] = v;
    __syncthreads();
    for (int off = 1; off < 256; off <<= 1) {
        int t = (tid >= off) ? sm[tid - off] : 0;
        __syncthreads();
        sm[tid] += t;
        __syncthreads();
    }
    if (i < n) offsets[i] = sm[tid] - v;
    if (tid == 255) blksum[blockIdx.x] = sm[255];
}

__global__ void ar1_scan2(const int* blksum, int* blkbase, int nb) {
    __shared__ int sm[256];
    int tid = threadIdx.x;
    int v = (tid < nb) ? blksum[tid] : 0;
    sm[tid] = v;
    __syncthreads();
    for (int off = 1; off < 256; off <<= 1) {
        int t = (tid >= off) ? sm[tid - off] : 0;
        __syncthreads();
        sm[tid] += t;
        __syncthreads();
    }
    if (tid < nb) blkbase[tid] = sm[tid] - v;
}

__global__ void ar1_scan3(const int* indeg, int* offsets, int* cursor,
                          const int* blkbase, float* dinv, int n) {
    int i = blockIdx.x * 256 + threadIdx.x;
    if (i < n) {
        int o = offsets[i] + blkbase[blockIdx.x];
        offsets[i] = o;
        cursor[i] = o;
        dinv[i] = rsqrtf((float)(indeg[i] + 1));   // +1: self loop
    }
}

__global__ void ar1_fill(const int* ei, const int* flagI, int* cursor,
                         int* csr, int E) {
    int e = blockIdx.x * 256 + threadIdx.x;
    if (e < E) {
        int is64 = flagI[0];
        int s = is64 ? ei[2 * e] : ei[e];
        int d = is64 ? ei[2 * (E + e)] : ei[E + e];
        if ((unsigned)s < (unsigned)GN && (unsigned)d < (unsigned)GN) {
            int p = atomicAdd(&cursor[d], 1);
            csr[p] = s;
        }
    }
}

// x -> bf16 row-major (copy if already bf16, round if fp32)
__global__ void ar1_cvt_bf16(const void* src, unsigned short* dst, int n,
                             const int* flagF) {
    int i = blockIdx.x * 256 + threadIdx.x;
    if (i < n) {
        if (flagF[0]) dst[i] = ar1_f2b(((const float*)src)[i]);
        else          dst[i] = ((const unsigned short*)src)[i];
    }
}

// fused small-vector -> fp32 conversion (biases, gamma, beta, lw4)
struct SmallCvt {
    const void* src[14];
    float* dst[14];
    int n[14];
};
__global__ void ar1_cvt_small(SmallCvt sc, const int* flagF) {
    int f = flagF[0];
    for (int s = 0; s < 14; s++) {
        for (int i = threadIdx.x; i < sc.n[s]; i += 256) {
            float v = f ? ((const float*)sc.src[s])[i]
                        : ar1_b2f(((const unsigned short*)sc.src[s])[i]);
            sc.dst[s][i] = v;
        }
    }
}

// pack W[K][M] into MFMA B-fragment order:
// Bp[(frag*64+lane)*8+j] = bf16(W[(c*32+(lane>>4)*8+j)*M + t*16+(lane&15)])
// where frag = t*(K/32)+c
__global__ void ar1_pack(const void* W, unsigned short* Bp, int K, int M,
                         const int* flagF) {
    int frag = blockIdx.x;
    int lane = threadIdx.x;     // 64
    int nch = K >> 5;
    int t = frag / nch, c = frag - t * nch;
    int n = t * 16 + (lane & 15);
    int k0 = c * 32 + (lane >> 4) * 8;
    int f = flagF[0];
    unsigned short* o = Bp + ((size_t)frag * 64 + lane) * 8;
    for (int j = 0; j < 8; j++) {
        int idx = (k0 + j) * M + n;
        o[j] = f ? ar1_f2b(((const float*)W)[idx])
                 : ((const unsigned short*)W)[idx];
    }
}

// ---------------- MFMA GEMM: C[GN,M] = A[GN,K] @ W[K,M] (+bias)(+relu) ------
// A,C bf16 row-major; Bp packed fragments; fp32 accum. NT = M/16.
// 256 threads = 4 waves; wave handles 16 rows x M cols; K multiple of 32.
template <int NT>
__global__ __launch_bounds__(256, 2)
void ar1_mfma(const unsigned short* __restrict__ A,
              const unsigned short* __restrict__ Bp,
              const float* __restrict__ bias,
              unsigned short* __restrict__ C, int K, int relu) {
    const int M = NT * 16;
    int tid = (int)threadIdx.x;
    int wv = tid >> 6, lane = tid & 63;
    int mb = ((int)blockIdx.x * 4 + wv) * 16;
    int m = lane & 15, quad = lane >> 4;
    int arow = mb + m;
    if (arow >= GN) arow = GN - 1;          // clamp; rows >= GN never stored
    const unsigned short* Aptr = A + (size_t)arow * K + quad * 8;
    int nch = K >> 5;

    floatx4 acc[NT];
#pragma unroll
    for (int t = 0; t < NT; t++) acc[t] = (floatx4){0.f, 0.f, 0.f, 0.f};

    for (int c = 0; c < nch; c++) {
        bf16x8 a = *((const bf16x8*)(Aptr + c * 32));
#pragma unroll
        for (int t = 0; t < NT; t++) {
            bf16x8 b = *((const bf16x8*)(Bp + ((size_t)(t * nch + c) * 64 + lane) * 8));
            acc[t] = __builtin_amdgcn_mfma_f32_16x16x32_bf16(a, b, acc[t], 0, 0, 0);
        }
    }

#pragma unroll
    for (int t = 0; t < NT; t++) {
#pragma unroll
        for (int r = 0; r < 4; r++) {
            int row = mb + quad * 4 + r;
            int col = t * 16 + m;
            if (row < GN) {
                float v = acc[t][r];
                if (bias) v += bias[col];
                if (relu) v = fmaxf(v, 0.f);
                C[(size_t)row * M + col] = ar1_f2b(v);
            }
        }
    }
}

// GCN aggregate (96 feats, bf16 in/out) + bias + BN(eval) + ReLU
__global__ void ar1_agg(const unsigned short* H, const int* offsets,
                        const int* indeg, const int* csr, const float* dinv,
                        const float* bias, const float* gamma, const float* beta,
                        unsigned short* Out) {
    __shared__ int   s_src[128];
    __shared__ float s_w[128];
    int node = blockIdx.x;
    int tid = threadIdx.x;
    float di = dinv[node];
    int off = offsets[node];
    int cnt = indeg[node];
    float acc = 0.f;
    for (int base = 0; base < cnt; base += 128) {
        int m = cnt - base;
        if (m > 128) m = 128;
        if (tid < m) {
            int s = csr[off + base + tid];
            if ((unsigned)s >= (unsigned)GN) s = node;
            s_src[tid] = s;
            s_w[tid] = dinv[s] * di;
        }
        __syncthreads();
        if (tid < 96) {
            for (int e = 0; e < m; e++)
                acc += s_w[e] * ar1_b2f(H[(size_t)s_src[e] * 96 + tid]);
        }
        __syncthreads();
    }
    if (tid < 96) {
        acc += di * di * ar1_b2f(H[(size_t)node * 96 + tid]);   // self loop
        float v = acc + bias[tid];
        v = v * 0.9999950000374997f * gamma[tid] + beta[tid];   // 1/sqrt(1+1e-5)
        Out[(size_t)node * 96 + tid] = ar1_f2b(fmaxf(v, 0.f));
    }
}

// final 64->8 layer (A bf16, W/bias fp32); writes fp32 or bf16 per flagF
__global__ void Arthur1_16458314678864_kernel(const unsigned short* A,
                                              const float* W, const float* bias,
                                              void* out, const int* flagF) {
    int i = blockIdx.x * 256 + threadIdx.x;
    if (i >= GN * 8) return;
    int node = i >> 3;
    int j = i & 7;
    const unsigned short* Ar = A + (size_t)node * 64;
    float v = bias[j];
    for (int k = 0; k < 64; k++) v += ar1_b2f(Ar[k]) * W[k * 8 + j];
    if (flagF[0]) ((float*)out)[i] = v;
    else ((unsigned short*)out)[i] = ar1_f2b(v);
}

extern "C" void kernel_launch(void* const* d_in, const int* in_sizes, int n_in,
                              void* d_out, int out_size, void* d_ws, size_t ws_size,
                              hipStream_t stream) {
    (void)in_sizes; (void)n_in; (void)out_size;

    // workspace layout
    char* p = (char*)d_ws;
    unsigned short* bufB = (unsigned short*)p; p += (size_t)GN * 256 * 2;  // 25.6 MB
    unsigned short* bufA = (unsigned short*)p; p += (size_t)GN * 128 * 2;  // 12.8 MB
    unsigned short* bufX = (unsigned short*)p; p += (size_t)GN * 64 * 2;   // 6.4 MB
    int* indeg  = (int*)p;    p += (size_t)GN * 4;
    int* offs   = (int*)p;    p += (size_t)GN * 4;
    int* cursor = (int*)p;    p += (size_t)GN * 4;
    int* blksum = (int*)p;    p += 1024;
    int* blkbase= (int*)p;    p += 1024;
    int* flagI  = (int*)p;    p += 1024;
    int* flagF  = (int*)p;    p += 1024;
    float* dinv = (float*)p;  p += (size_t)GN * 4;
    int* csr    = (int*)p;    p += (size_t)GE * 4;
    unsigned short* bpArena = (unsigned short*)p; p += 90112 * 2;  // packed W
    float* fArena = (float*)p; p += 2048 * 4;                      // small fp32
    size_t need = (size_t)(p - (char*)d_ws);
    if (ws_size < need) {
        hipMemsetAsync(d_out, 0x41, (size_t)GN * 8 * 2, stream);  // marker 12.06
        return;
    }

    // packed-weight arena offsets (shorts): w1,w2,w3,lw1,lw2,lw3
    unsigned short* bp_w1  = bpArena;             // 6144
    unsigned short* bp_w2  = bp_w1 + 6144;        // 9216
    unsigned short* bp_w3  = bp_w2 + 9216;        // 9216
    unsigned short* bp_lw1 = bp_w3 + 9216;        // 24576
    unsigned short* bp_lw2 = bp_lw1 + 24576;      // 32768
    unsigned short* bp_lw3 = bp_lw2 + 32768;      // 8192

    // small fp32 arena: b1,g1,be1,b2,g2,be2,b3,g3,be3 (96 each), lb1(256),
    // lb2(128), lb3(64), lb4(8), lw4(512)
    float* fs[14];
    int fn[14] = {96,96,96, 96,96,96, 96,96,96, 256,128,64,8, 512};
    int fsrc[14] = {3,4,5, 7,8,9, 11,12,13, 15,17,19,21, 20};
    {
        float* q = fArena;
        for (int i = 0; i < 14; i++) { fs[i] = q; q += fn[i]; }
    }

    const int* ei = (const int*)d_in[1];
    const int NB = (GN + 255) / 256;
    const int EB = (GE + 255) / 256;

    ar1_detect_idx<<<1, 256, 0, stream>>>(ei, flagI);
    ar1_detect_f<<<1, 256, 0, stream>>>((const unsigned short*)d_in[0], flagF);
    ar1_zero<<<NB, 256, 0, stream>>>(indeg, GN);
    ar1_count<<<EB, 256, 0, stream>>>(ei, flagI, indeg, GE);
    ar1_scan1<<<NB, 256, 0, stream>>>(indeg, offs, blksum, GN);
    ar1_scan2<<<1, 256, 0, stream>>>(blksum, blkbase, NB);
    ar1_scan3<<<NB, 256, 0, stream>>>(indeg, offs, cursor, blkbase, dinv, GN);
    ar1_fill<<<EB, 256, 0, stream>>>(ei, flagI, cursor, csr, GE);

    // conversions
    ar1_cvt_bf16<<<(GN * 64 + 255) / 256, 256, 0, stream>>>(d_in[0], bufX, GN * 64, flagF);
    {
        SmallCvt sc;
        for (int i = 0; i < 14; i++) { sc.src[i] = d_in[fsrc[i]]; sc.dst[i] = fs[i]; sc.n[i] = fn[i]; }
        ar1_cvt_small<<<1, 256, 0, stream>>>(sc, flagF);
    }
    ar1_pack<<<2 * 6,  64, 0, stream>>>(d_in[2],  bp_w1,  64,  96, flagF);
    ar1_pack<<<3 * 6,  64, 0, stream>>>(d_in[6],  bp_w2,  96,  96, flagF);
    ar1_pack<<<3 * 6,  64, 0, stream>>>(d_in[10], bp_w3,  96,  96, flagF);
    ar1_pack<<<3 * 16, 64, 0, stream>>>(d_in[14], bp_lw1, 96, 256, flagF);
    ar1_pack<<<8 * 8,  64, 0, stream>>>(d_in[16], bp_lw2, 256, 128, flagF);
    ar1_pack<<<4 * 4,  64, 0, stream>>>(d_in[18], bp_lw3, 128, 64, flagF);

    const int GB = (GN + 63) / 64;   // 64 rows per block (4 waves x 16)

    // GCN 1..3 (bias=null: bias/BN/ReLU fused in agg)
    ar1_mfma<6><<<GB, 256, 0, stream>>>(bufX, bp_w1, (const float*)0, bufB, 64, 0);
    ar1_agg<<<GN, 128, 0, stream>>>(bufB, offs, indeg, csr, dinv, fs[0], fs[1], fs[2], bufA);
    ar1_mfma<6><<<GB, 256, 0, stream>>>(bufA, bp_w2, (const float*)0, bufB, 96, 0);
    ar1_agg<<<GN, 128, 0, stream>>>(bufB, offs, indeg, csr, dinv, fs[3], fs[4], fs[5], bufA);
    ar1_mfma<6><<<GB, 256, 0, stream>>>(bufA, bp_w3, (const float*)0, bufB, 96, 0);
    ar1_agg<<<GN, 128, 0, stream>>>(bufB, offs, indeg, csr, dinv, fs[6], fs[7], fs[8], bufA);

    // MLP: 96->256->128->64->8
    ar1_mfma<16><<<GB, 256, 0, stream>>>(bufA, bp_lw1, fs[9],  bufB, 96, 1);
    ar1_mfma<8><<<GB, 256, 0, stream>>>(bufB, bp_lw2, fs[10], bufA, 256, 1);
    ar1_mfma<4><<<GB, 256, 0, stream>>>(bufA, bp_lw3, fs[11], bufB, 128, 1);
    Arthur1_16458314678864_kernel<<<(GN * 8 + 255) / 256, 256, 0, stream>>>(
        bufB, fs[13], fs[12], d_out, flagF);
}

// Round 11
// 448.029 us; speedup vs baseline: 6.0545x; 1.0641x over previous
//
#include <hip/hip_runtime.h>

// GCN(3 layers) + MLP(4 layers), N=50000, E=800000, out = N x 8 bf16.
// NOTE: do NOT include <hip/hip_bf16.h> — breaks this harness's build
// (rounds 1-4 fell back to a stub; round 5 proved it). Manual bf16 ushort ops.
// Dtype runtime-detection: flagI (edge_index int64 vs int32), flagF (floats
// fp32 vs packed bf16).
//
// R11: (a) agg v2 — H padded to 128 bf16/row; wave-per-node gathers 4 edge
// rows x 16B vector loads per instruction (R10 agg was latency-bound: 51us,
// 1.7 TB/s, scalar 2B reads, half-wave idle); shfl_xor reduce + fused
// self-loop/bias/BN/ReLU. (b) GEMMs take Astride/Cstride/Mout (padded rows).
// (c) final 64->8 layer via mfma NT=1; 6 pack launches fused to 1.

#define GN 50000
#define GE 800000

typedef __attribute__((ext_vector_type(8))) short bf16x8;
typedef __attribute__((ext_vector_type(4))) float floatx4;

__device__ __forceinline__ float ar1_b2f(unsigned short h) {
    return __uint_as_float(((unsigned)h) << 16);
}
__device__ __forceinline__ unsigned short ar1_f2b(float f) {
    unsigned u = __float_as_uint(f);
    u = u + 0x7FFFu + ((u >> 16) & 1u);   // round-to-nearest-even
    return (unsigned short)(u >> 16);
}

__global__ void ar1_zero(int* p, int n) {
    int i = blockIdx.x * 256 + threadIdx.x;
    if (i < n) p[i] = 0;
}

// flagI[0]=1 => edge_index is int64
__global__ void ar1_detect_idx(const int* ei, int* flagI) {
    __shared__ int cnt;
    if (threadIdx.x == 0) cnt = 0;
    __syncthreads();
    if (ei[2 * threadIdx.x + 1] != 0) atomicAdd(&cnt, 1);
    __syncthreads();
    if (threadIdx.x == 0) flagI[0] = (cnt < 8) ? 1 : 0;
}

// flagF[0]=1 => float tensors are fp32; 0 => packed bf16 (see R6 notes).
__global__ void ar1_detect_f(const unsigned short* xw, int* flagF) {
    __shared__ int cnt;
    if (threadIdx.x == 0) cnt = 0;
    __syncthreads();
    unsigned short w = xw[2 * threadIdx.x];
    int ex = (w >> 7) & 0xFF;
    if (w == 0 || (ex >= 90 && ex <= 150)) atomicAdd(&cnt, 1);
    __syncthreads();
    if (threadIdx.x == 0) flagF[0] = (cnt > 200) ? 0 : 1;
}

__global__ void ar1_count(const int* ei, const int* flagI, int* indeg, int E) {
    int e = blockIdx.x * 256 + threadIdx.x;
    if (e < E) {
        int d = flagI[0] ? ei[2 * (E + e)] : ei[E + e];
        if ((unsigned)d < (unsigned)GN) atomicAdd(&indeg[d], 1);
    }
}

__global__ void ar1_scan1(const int* indeg, int* offsets, int* blksum, int n) {
    __shared__ int sm[256];
    int tid = threadIdx.x;
    int i = blockIdx.x * 256 + tid;
    int v = (i < n) ? indeg[i] : 0;
    sm[tid] = v;
    __syncthreads();
    for (int off = 1; off < 256; off <<= 1) {
        int t = (tid >= off) ? sm[tid - off] : 0;
        __syncthreads();
        sm[tid] += t;
        __syncthreads();
    }
    if (i < n) offsets[i] = sm[tid] - v;
    if (tid == 255) blksum[blockIdx.x] = sm[255];
}

__global__ void ar1_scan2(const int* blksum, int* blkbase, int nb) {
    __shared__ int sm[256];
    int tid = threadIdx.x;
    int v = (tid < nb) ? blksum[tid] : 0;
    sm[tid] = v;
    __syncthreads();
    for (int off = 1; off < 256; off <<= 1) {
        int t = (tid >= off) ? sm[tid - off] : 0;
        __syncthreads();
        sm[tid] += t;
        __syncthreads();
    }
    if (tid < nb) blkbase[tid] = sm[tid] - v;
}

__global__ void ar1_scan3(const int* indeg, int* offsets, int* cursor,
                          const int* blkbase, float* dinv, int n) {
    int i = blockIdx.x * 256 + threadIdx.x;
    if (i < n) {
        int o = offsets[i] + blkbase[blockIdx.x];
        offsets[i] = o;
        cursor[i] = o;
        dinv[i] = rsqrtf((float)(indeg[i] + 1));   // +1: self loop
    }
}

__global__ void ar1_fill(const int* ei, const int* flagI, int* cursor,
                         int* csr, int E) {
    int e = blockIdx.x * 256 + threadIdx.x;
    if (e < E) {
        int is64 = flagI[0];
        int s = is64 ? ei[2 * e] : ei[e];
        int d = is64 ? ei[2 * (E + e)] : ei[E + e];
        if ((unsigned)s < (unsigned)GN && (unsigned)d < (unsigned)GN) {
            int p = atomicAdd(&cursor[d], 1);
            csr[p] = s;
        }
    }
}

// x -> bf16 row-major (copy if already bf16, round if fp32)
__global__ void ar1_cvt_bf16(const void* src, unsigned short* dst, int n,
                             const int* flagF) {
    int i = blockIdx.x * 256 + threadIdx.x;
    if (i < n) {
        if (flagF[0]) dst[i] = ar1_f2b(((const float*)src)[i]);
        else          dst[i] = ((const unsigned short*)src)[i];
    }
}

// fused small-vector -> fp32 conversion (biases, gamma, beta)
struct SmallCvt {
    const void* src[13];
    float* dst[13];
    int n[13];
};
__global__ void ar1_cvt_small(SmallCvt sc, const int* flagF) {
    int f = flagF[0];
    for (int s = 0; s < 13; s++) {
        for (int i = threadIdx.x; i < sc.n[s]; i += 256) {
            float v = f ? ((const float*)sc.src[s])[i]
                        : ar1_b2f(((const unsigned short*)sc.src[s])[i]);
            sc.dst[s][i] = v;
        }
    }
}

// fused pack of all 7 weights into MFMA B-fragment order:
// Bp[(frag*64+lane)*8+j] = bf16(W[(c*32+(lane>>4)*8+j)*M + t*16+(lane&15)]),
// frag = t*(K/32)+c; n >= M reads as 0 (lw4 M=8 padding).
struct PackAll {
    const void* src[7];
    unsigned short* dst[7];
    int K[7], M[7], start[8];
};
__global__ void ar1_pack_all(PackAll pa, const int* flagF) {
    int b = (int)blockIdx.x;
    int w = 0;
    while (w < 6 && b >= pa.start[w + 1]) w++;
    int frag = b - pa.start[w];
    int K = pa.K[w], M = pa.M[w];
    int lane = (int)threadIdx.x;
    int nch = K >> 5;
    int t = frag / nch, c = frag - t * nch;
    int n = t * 16 + (lane & 15);
    int k0 = c * 32 + (lane >> 4) * 8;
    int f = flagF[0];
    unsigned short* o = pa.dst[w] + ((size_t)frag * 64 + lane) * 8;
    for (int j = 0; j < 8; j++) {
        unsigned short v = 0;
        if (n < M) {
            int idx = (k0 + j) * M + n;
            v = f ? ar1_f2b(((const float*)pa.src[w])[idx])
                  : ((const unsigned short*)pa.src[w])[idx];
        }
        o[j] = v;
    }
}

// ---------------- MFMA GEMM: C[GN,Mout] = A[GN,K] @ W[K,M] (+bias)(+relu) ---
// A bf16 rows of Astride; C rows of Cstride (bf16, or fp32 if f32out&&*f32out).
// Bp packed fragments; fp32 accum; NT*16 = padded M; K mult of 32.
template <int NT>
__global__ __launch_bounds__(256, 2)
void ar1_mfma(const unsigned short* __restrict__ A,
              const unsigned short* __restrict__ Bp,
              const float* __restrict__ bias,
              void* __restrict__ C, int K, int Astride, int Cstride,
              int Mout, int relu, const int* f32out) {
    int tid = (int)threadIdx.x;
    int wv = tid >> 6, lane = tid & 63;
    int mb = ((int)blockIdx.x * 4 + wv) * 16;
    int m = lane & 15, quad = lane >> 4;
    int arow = mb + m;
    if (arow >= GN) arow = GN - 1;          // clamp; rows >= GN never stored
    const unsigned short* Aptr = A + (size_t)arow * Astride + quad * 8;
    int nch = K >> 5;

    floatx4 acc[NT];
#pragma unroll
    for (int t = 0; t < NT; t++) acc[t] = (floatx4){0.f, 0.f, 0.f, 0.f};

    for (int c = 0; c < nch; c++) {
        bf16x8 a = *((const bf16x8*)(Aptr + c * 32));
#pragma unroll
        for (int t = 0; t < NT; t++) {
            bf16x8 b = *((const bf16x8*)(Bp + ((size_t)(t * nch + c) * 64 + lane) * 8));
            acc[t] = __builtin_amdgcn_mfma_f32_16x16x32_bf16(a, b, acc[t], 0, 0, 0);
        }
    }

    int wf32 = (f32out != (const int*)0) ? f32out[0] : 0;
#pragma unroll
    for (int t = 0; t < NT; t++) {
#pragma unroll
        for (int r = 0; r < 4; r++) {
            int row = mb + quad * 4 + r;
            int col = t * 16 + m;
            if (row < GN && col < Mout) {
                float v = acc[t][r];
                if (bias) v += bias[col];
                if (relu) v = fmaxf(v, 0.f);
                if (wf32) ((float*)C)[(size_t)row * Cstride + col] = v;
                else ((unsigned short*)C)[(size_t)row * Cstride + col] = ar1_f2b(v);
            }
        }
    }
}

// ---------------- GCN aggregate v2 ------------------------------------------
// H rows padded to 128 bf16 (256 B). Wave per node: lane = eslot(2b) x chunk
// (4b); per iteration gathers 4 edge rows x 16B; fp32 acc x8/lane; shfl_xor
// reduce over eslots; fused self-loop + bias + BN(eval) + ReLU. 4 nodes/blk.
__global__ __launch_bounds__(256, 4)
void ar1_agg2(const unsigned short* __restrict__ H, const int* __restrict__ offs,
              const int* __restrict__ indeg, const int* __restrict__ csr,
              const float* __restrict__ dinv,
              const float* __restrict__ bias, const float* __restrict__ gamma,
              const float* __restrict__ beta, unsigned short* __restrict__ Out) {
    int wv = (int)threadIdx.x >> 6, lane = (int)threadIdx.x & 63;
    int node = (int)blockIdx.x * 4 + wv;
    if (node >= GN) return;
    int chunk = lane & 15;     // feature chunk: feats chunk*8 .. +8
    int eslot = lane >> 4;     // 0..3
    float di = dinv[node];
    int off = offs[node], cnt = indeg[node];

    float acc[8];
#pragma unroll
    for (int j = 0; j < 8; j++) acc[j] = 0.f;

    for (int base = 0; base < cnt; base += 4) {
        int e = base + eslot;
        int s = node;
        float w = 0.f;
        if (e < cnt) {
            s = csr[off + e];
            if ((unsigned)s >= (unsigned)GN) s = node;
            w = dinv[s] * di;
        }
        bf16x8 h = *((const bf16x8*)(H + (size_t)s * 128 + chunk * 8));
#pragma unroll
        for (int j = 0; j < 8; j++)
            acc[j] += w * ar1_b2f((unsigned short)h[j]);
    }

    // reduce partial sums across the 4 edge-slot groups
#pragma unroll
    for (int j = 0; j < 8; j++) {
        acc[j] += __shfl_xor(acc[j], 16, 64);
        acc[j] += __shfl_xor(acc[j], 32, 64);
    }

    if (eslot == 0 && chunk < 12) {
        bf16x8 hs = *((const bf16x8*)(H + (size_t)node * 128 + chunk * 8));
#pragma unroll
        for (int j = 0; j < 8; j++) {
            int f = chunk * 8 + j;
            float v = acc[j] + di * di * ar1_b2f((unsigned short)hs[j]) + bias[f];
            v = v * 0.9999950000374997f * gamma[f] + beta[f];   // 1/sqrt(1+1e-5)
            Out[(size_t)node * 128 + f] = ar1_f2b(fmaxf(v, 0.f));
        }
    }
}

// keep harness-expected symbol alive as a no-op-named real kernel (final mfma
// does the work); this name is also used for the x conversion launch below.
__global__ void Arthur1_16458314678864_kernel(const void* src,
                                              unsigned short* dst, int n,
                                              const int* flagF) {
    int i = blockIdx.x * 256 + threadIdx.x;
    if (i < n) {
        if (flagF[0]) dst[i] = ar1_f2b(((const float*)src)[i]);
        else          dst[i] = ((const unsigned short*)src)[i];
    }
}

extern "C" void kernel_launch(void* const* d_in, const int* in_sizes, int n_in,
                              void* d_out, int out_size, void* d_ws, size_t ws_size,
                              hipStream_t stream) {
    (void)in_sizes; (void)n_in; (void)out_size;

    // workspace layout
    char* p = (char*)d_ws;
    unsigned short* bufB = (unsigned short*)p; p += (size_t)GN * 256 * 2;  // 25.6 MB
    unsigned short* bufA = (unsigned short*)p; p += (size_t)GN * 128 * 2;  // 12.8 MB
    unsigned short* bufX = (unsigned short*)p; p += (size_t)GN * 64 * 2;   // 6.4 MB
    int* indeg  = (int*)p;    p += (size_t)GN * 4;
    int* offs   = (int*)p;    p += (size_t)GN * 4;
    int* cursor = (int*)p;    p += (size_t)GN * 4;
    int* blksum = (int*)p;    p += 1024;
    int* blkbase= (int*)p;    p += 1024;
    int* flagI  = (int*)p;    p += 1024;
    int* flagF  = (int*)p;    p += 1024;
    float* dinv = (float*)p;  p += (size_t)GN * 4;
    int* csr    = (int*)p;    p += (size_t)GE * 4;
    unsigned short* bpArena = (unsigned short*)p; p += 91136 * 2;  // packed W
    float* fArena = (float*)p; p += 2048 * 4;                      // small fp32
    size_t need = (size_t)(p - (char*)d_ws);
    if (ws_size < need) {
        hipMemsetAsync(d_out, 0x41, (size_t)GN * 8 * 2, stream);  // marker 12.06
        return;
    }

    // packed-weight arena offsets (shorts): w1,w2,w3,lw1,lw2,lw3,lw4
    unsigned short* bp[7];
    int bpn[7] = {6144, 9216, 9216, 24576, 32768, 8192, 1024};
    {
        unsigned short* q = bpArena;
        for (int i = 0; i < 7; i++) { bp[i] = q; q += bpn[i]; }
    }

    // small fp32 arena: b1,g1,be1,b2,g2,be2,b3,g3,be3, lb1,lb2,lb3,lb4
    float* fs[13];
    int fn[13] = {96,96,96, 96,96,96, 96,96,96, 256,128,64,8};
    int fsrc[13] = {3,4,5, 7,8,9, 11,12,13, 15,17,19,21};
    {
        float* q = fArena;
        for (int i = 0; i < 13; i++) { fs[i] = q; q += fn[i]; }
    }

    const int* ei = (const int*)d_in[1];
    const int NB = (GN + 255) / 256;
    const int EB = (GE + 255) / 256;

    ar1_detect_idx<<<1, 256, 0, stream>>>(ei, flagI);
    ar1_detect_f<<<1, 256, 0, stream>>>((const unsigned short*)d_in[0], flagF);
    ar1_zero<<<NB, 256, 0, stream>>>(indeg, GN);
    ar1_count<<<EB, 256, 0, stream>>>(ei, flagI, indeg, GE);
    ar1_scan1<<<NB, 256, 0, stream>>>(indeg, offs, blksum, GN);
    ar1_scan2<<<1, 256, 0, stream>>>(blksum, blkbase, NB);
    ar1_scan3<<<NB, 256, 0, stream>>>(indeg, offs, cursor, blkbase, dinv, GN);
    ar1_fill<<<EB, 256, 0, stream>>>(ei, flagI, cursor, csr, GE);

    // conversions
    Arthur1_16458314678864_kernel<<<(GN * 64 + 255) / 256, 256, 0, stream>>>(
        d_in[0], bufX, GN * 64, flagF);
    {
        SmallCvt sc;
        for (int i = 0; i < 13; i++) { sc.src[i] = d_in[fsrc[i]]; sc.dst[i] = fs[i]; sc.n[i] = fn[i]; }
        ar1_cvt_small<<<1, 256, 0, stream>>>(sc, flagF);
    }
    {
        PackAll pa;
        int wsrc[7] = {2, 6, 10, 14, 16, 18, 20};
        int Ks[7] = {64, 96, 96, 96, 256, 128, 64};
        int Ms[7] = {96, 96, 96, 256, 128, 64, 8};
        int cum = 0;
        for (int i = 0; i < 7; i++) {
            pa.src[i] = d_in[wsrc[i]]; pa.dst[i] = bp[i];
            pa.K[i] = Ks[i]; pa.M[i] = Ms[i];
            pa.start[i] = cum;
            cum += (Ms[i] + 15) / 16 * (Ks[i] / 32);
        }
        pa.start[7] = cum;   // 178
        ar1_pack_all<<<cum, 64, 0, stream>>>(pa, flagF);
    }

    const int GB = (GN + 63) / 64;    // 64 rows per block (4 waves x 16)
    const int AB = GN / 4;            // agg2: 4 nodes per block (12500 exact)

    // GCN 1..3 (A stride / C stride 128-padded; bias/BN/ReLU fused in agg)
    ar1_mfma<6><<<GB, 256, 0, stream>>>(bufX, bp[0], (const float*)0, bufB, 64, 64, 128, 96, 0, (const int*)0);
    ar1_agg2<<<AB, 256, 0, stream>>>(bufB, offs, indeg, csr, dinv, fs[0], fs[1], fs[2], bufA);
    ar1_mfma<6><<<GB, 256, 0, stream>>>(bufA, bp[1], (const float*)0, bufB, 96, 128, 128, 96, 0, (const int*)0);
    ar1_agg2<<<AB, 256, 0, stream>>>(bufB, offs, indeg, csr, dinv, fs[3], fs[4], fs[5], bufA);
    ar1_mfma<6><<<GB, 256, 0, stream>>>(bufA, bp[2], (const float*)0, bufB, 96, 128, 128, 96, 0, (const int*)0);
    ar1_agg2<<<AB, 256, 0, stream>>>(bufB, offs, indeg, csr, dinv, fs[6], fs[7], fs[8], bufA);

    // MLP: 96->256->128->64->8 (last layer writes d_out, fp32/bf16 per flagF)
    ar1_mfma<16><<<GB, 256, 0, stream>>>(bufA, bp[3], fs[9],  bufB, 96, 128, 256, 256, 1, (const int*)0);
    ar1_mfma<8><<<GB, 256, 0, stream>>>(bufB, bp[4], fs[10], bufA, 256, 256, 128, 128, 1, (const int*)0);
    ar1_mfma<4><<<GB, 256, 0, stream>>>(bufA, bp[5], fs[11], bufB, 128, 128, 64, 64, 1, (const int*)0);
    ar1_mfma<1><<<GB, 256, 0, stream>>>(bufB, bp[6], fs[12], d_out, 64, 64, 8, 8, 0, flagF);
}